// Round 10
// baseline (27.972 us; speedup 1.0000x reference)
//
#include <hip/hip_runtime.h>
#include <math.h>

#define NQ 4
#define NL 6
#define BATCH 524288
#define LP 17      // padded row stride (float2) for V-build matmuls
#define NPASS 16   // elements per block = 64 * NPASS
#define NBLK (BATCH / (64 * NPASS))   // 512 blocks

struct C2 { float re, im; };

__device__ __forceinline__ C2 cmul(C2 a, C2 b) {
    return C2{ __builtin_fmaf(a.re, b.re, -a.im * b.im),
               __builtin_fmaf(a.re, b.im,  a.im * b.re) };
}

__device__ __forceinline__ float rfl(float v) {
    return __uint_as_float(__builtin_amdgcn_readfirstlane(__float_as_uint(v)));
}

// ---------------------------------------------------------------------------
// ONE kernel, one graph node, SGPR-resident V in the hot loop.
// Block = 512 threads (8 waves), 512 blocks, 1024 elements/block.
//   A) threads<256: build V via gate-product + log-depth tree matmul
//      (verbatim R9, ~2us, proven) -> sVf[16*32]                 [barriers]
//   B) wave w extracts rows {2w, 2w+1} of V into 64 SGPRs
//      (uniform ds_read + readfirstlane, one-time)
//   C) NPASS passes: lanes = 64 elements; per element this wave computes
//      its 2 rows' |psi_r|^2 with 64 fma whose V operands are SGPRs
//      (zero vector-load traffic); signed partial -> sEv (contiguous LDS).
//      Rotating reducer wave sums 8 partials/elem from the previous pass
//      (double-buffered, 1 barrier/pass) and stores float4 to out.
// Rationale: R2/R5/R9 matvecs all cost ~16us because broadcast vector loads
// deliver 16B x 64 lanes per instr (return-bandwidth bound, same for LDS and
// global). SGPR operands bypass that path entirely.
// ---------------------------------------------------------------------------
__global__ __launch_bounds__(512) void qsg_kernel(const float4* __restrict__ x,
                                                  const float* __restrict__ w,
                                                  float4* __restrict__ out) {
    __shared__ float  sU[NL * NQ * 8];
    __shared__ float2 sL[NL][16 * LP];
    __shared__ float2 sP[3][16 * LP];
    __shared__ float2 sDm[16 * LP];
    __shared__ float  sVf[16 * 32];          // V[r][c] -> (re,im) at r*32+2c
    __shared__ float4 sEv[2][8 * 64];        // double-buffered partials

    const int tid  = threadIdx.x;
    const int lane = tid & 63;
    const int wv   = tid >> 6;               // wave 0..7

    // ---- A1) fused gate matrices (24 threads) ----
    if (tid < NL * NQ) {
        const float a = w[tid * 3 + 0];
        const float b = w[tid * 3 + 1];
        const float g = w[tid * 3 + 2];
        float ca, sa, cb, sb, cg, sg;
        sincosf(0.5f * a, &sa, &ca);
        sincosf(0.5f * b, &sb, &cb);
        sincosf(0.5f * g, &sg, &cg);
        C2 M00{cb * ca,  sb * sa};
        C2 M01{-sb * ca, -cb * sa};
        C2 M10{sb * ca,  -cb * sa};
        C2 M11{cb * ca,  -sb * sa};
        C2 em{cg, -sg}, ep{cg, sg};
        C2 U00 = cmul(em, M00), U01 = cmul(em, M01);
        C2 U10 = cmul(ep, M10), U11 = cmul(ep, M11);
        float* o = &sU[tid * 8];
        o[0] = U00.re; o[1] = U00.im; o[2] = U01.re; o[3] = U01.im;
        o[4] = U10.re; o[5] = U10.im; o[6] = U11.re; o[7] = U11.im;
    }
    __syncthreads();

    // ---- A2) layer matrices L_l[r][c] = prod_q U_q[r_q][perm(c)_q] ----
    if (tid < 256) {
        const int r = tid >> 4, c = tid & 15;
        int b0 = (c >> 3) & 1, b1 = (c >> 2) & 1, b2 = (c >> 1) & 1, b3 = c & 1;
        b1 ^= b0; b2 ^= b1; b3 ^= b2; b0 ^= b3;
        const int r0 = (r >> 3) & 1, r1 = (r >> 2) & 1, r2 = (r >> 1) & 1, r3 = r & 1;
        const int o0 = (r0 * 2 + b0) * 2;
        const int o1 = (r1 * 2 + b1) * 2;
        const int o2 = (r2 * 2 + b2) * 2;
        const int o3 = (r3 * 2 + b3) * 2;
#pragma unroll
        for (int l = 0; l < NL; ++l) {
            const float* g = &sU[l * 32];
            C2 a{g[o0], g[o0 + 1]};
            a = cmul(a, C2{g[8  + o1], g[8  + o1 + 1]});
            a = cmul(a, C2{g[16 + o2], g[16 + o2 + 1]});
            a = cmul(a, C2{g[24 + o3], g[24 + o3 + 1]});
            sL[l][r * LP + c] = make_float2(a.re, a.im);
        }
    }
    __syncthreads();

    // ---- A3) tree matmuls: A=L1*L0, B=L3*L2, C=L5*L4; D=B*A; V=C*D ----
    if (tid < 256) {
        const int r = tid >> 4, c = tid & 15;
#pragma unroll
        for (int s = 0; s < 3; ++s) {
            float re = 0.f, im = 0.f;
#pragma unroll
            for (int k = 0; k < 16; ++k) {
                const float2 xk = sL[2 * s + 1][r * LP + k];
                const float2 yk = sL[2 * s][k * LP + c];
                re = __builtin_fmaf(xk.x, yk.x, re); re = __builtin_fmaf(-xk.y, yk.y, re);
                im = __builtin_fmaf(xk.x, yk.y, im); im = __builtin_fmaf( xk.y, yk.x, im);
            }
            sP[s][r * LP + c] = make_float2(re, im);
        }
    }
    __syncthreads();
    if (tid < 256) {
        const int r = tid >> 4, c = tid & 15;
        float re = 0.f, im = 0.f;
#pragma unroll
        for (int k = 0; k < 16; ++k) {
            const float2 xk = sP[1][r * LP + k];
            const float2 yk = sP[0][k * LP + c];
            re = __builtin_fmaf(xk.x, yk.x, re); re = __builtin_fmaf(-xk.y, yk.y, re);
            im = __builtin_fmaf(xk.x, yk.y, im); im = __builtin_fmaf( xk.y, yk.x, im);
        }
        sDm[r * LP + c] = make_float2(re, im);
    }
    __syncthreads();
    if (tid < 256) {
        const int r = tid >> 4, c = tid & 15;
        float re = 0.f, im = 0.f;
#pragma unroll
        for (int k = 0; k < 16; ++k) {
            const float2 xk = sP[2][r * LP + k];
            const float2 yk = sDm[k * LP + c];
            re = __builtin_fmaf(xk.x, yk.x, re); re = __builtin_fmaf(-xk.y, yk.y, re);
            im = __builtin_fmaf(xk.x, yk.y, im); im = __builtin_fmaf( xk.y, yk.x, im);
        }
        // fold (-i)^popcount(c): 0:(a,b) 1:(b,-a) 2:(-a,-b) 3:(-b,a)
        const int p4 = __popc(c) & 3;
        float wr, wi;
        if      (p4 == 0) { wr = re;  wi = im;  }
        else if (p4 == 1) { wr = im;  wi = -re; }
        else if (p4 == 2) { wr = -re; wi = -im; }
        else              { wr = -im; wi = re;  }
        sVf[r * 32 + 2 * c]     = wr;
        sVf[r * 32 + 2 * c + 1] = wi;
    }
    __syncthreads();

    // ---- B) extract this wave's 2 rows into SGPRs ----
    const int row0 = 2 * wv, row1 = 2 * wv + 1;
    float uRe0[16], uIm0[16], uRe1[16], uIm1[16];
#pragma unroll
    for (int c = 0; c < 16; ++c) {
        const float2 v0 = *reinterpret_cast<const float2*>(&sVf[row0 * 32 + 2 * c]);
        const float2 v1 = *reinterpret_cast<const float2*>(&sVf[row1 * 32 + 2 * c]);
        uRe0[c] = rfl(v0.x); uIm0[c] = rfl(v0.y);
        uRe1[c] = rfl(v1.x); uIm1[c] = rfl(v1.y);
    }
    const float sg0 = (wv & 4) ? -1.f : 1.f;   // r&8 sign for rows 2w,2w+1
    const float sg1 = (wv & 2) ? -1.f : 1.f;   // r&4
    const float sg2 = (wv & 1) ? -1.f : 1.f;   // r&2

    const int gbase = blockIdx.x * (64 * NPASS);

    // ---- C) pass loop: compute partials; rotating wave reduces prev pass ----
    for (int p = 0; p <= NPASS; ++p) {
        if (p < NPASS) {
            const float4 xv = x[gbase + p * 64 + lane];
            float c0, s0, c1, s1, c2, s2, c3, s3;
            __sincosf(0.5f * xv.x, &s0, &c0);
            __sincosf(0.5f * xv.y, &s1, &c1);
            __sincosf(0.5f * xv.z, &s2, &c2);
            __sincosf(0.5f * xv.w, &s3, &c3);
            float m[16];
            {
                float ab[4];
                ab[0] = c0 * c1; ab[1] = c0 * s1; ab[2] = s0 * c1; ab[3] = s0 * s1;
                float abc[8];
#pragma unroll
                for (int k = 0; k < 4; ++k) { abc[2 * k] = ab[k] * c2; abc[2 * k + 1] = ab[k] * s2; }
#pragma unroll
                for (int k = 0; k < 8; ++k) { m[2 * k] = abc[k] * c3; m[2 * k + 1] = abc[k] * s3; }
            }
            float re0 = 0.f, im0 = 0.f, re1 = 0.f, im1 = 0.f;
#pragma unroll
            for (int c = 0; c < 16; ++c) {
                re0 = __builtin_fmaf(m[c], uRe0[c], re0);
                im0 = __builtin_fmaf(m[c], uIm0[c], im0);
                re1 = __builtin_fmaf(m[c], uRe1[c], re1);
                im1 = __builtin_fmaf(m[c], uIm1[c], im1);
            }
            const float p0 = __builtin_fmaf(re0, re0, im0 * im0);
            const float p1 = __builtin_fmaf(re1, re1, im1 * im1);
            const float S = p0 + p1;
            const float D = p0 - p1;
            sEv[p & 1][wv * 64 + lane] = make_float4(sg0 * S, sg1 * S, sg2 * S, D);
        }
        if (p > 0 && wv == ((p - 1) & 7)) {
            const int b = (p - 1) & 1;
            float4 a = sEv[b][lane];
#pragma unroll
            for (int ww = 1; ww < 8; ++ww) {
                const float4 t = sEv[b][ww * 64 + lane];
                a.x += t.x; a.y += t.y; a.z += t.z; a.w += t.w;
            }
            out[gbase + (p - 1) * 64 + lane] = a;
        }
        __syncthreads();
    }
}

extern "C" void kernel_launch(void* const* d_in, const int* in_sizes, int n_in,
                              void* d_out, int out_size, void* d_ws, size_t ws_size,
                              hipStream_t stream) {
    const float4* x = (const float4*)d_in[0];   // [B,4] f32
    const float*  w = (const float*)d_in[1];    // [6,4,3] f32
    float4* out = (float4*)d_out;               // [B,4] f32

    qsg_kernel<<<NBLK, 512, 0, stream>>>(x, w, out);
}